// Round 6
// baseline (1755.091 us; speedup 1.0000x reference)
//
#include <hip/hip_runtime.h>
#include <hip/hip_bf16.h>
#include <stdint.h>

// Problem constants
#define KVOL   27
#define MPAIRS 150000
#define NROWS  200000            // N_IN == N_OUT
#define CDIM   64
#define TOTALC (KVOL*MPAIRS)     // 4,050,000 contributions

// Bucketing
#define BROWS  128                       // output rows per bucket
#define NBKT   ((NROWS + BROWS - 1) / BROWS)   // 1563
#define NWG1   256                       // WGs for hist/scatter
#define CHUNK  ((TOTALC + NWG1 - 1) / NWG1)    // 15821
#define SCAN_N (NBKT * NWG1)             // 400,128
#define KCAP   3584                      // per-bucket entry capacity (mean 2590, sd 51)
#define DUMMY  0x40000000u               // outl=128 -> garbage accum row

typedef __attribute__((ext_vector_type(8))) short bf16x8;
typedef __attribute__((ext_vector_type(4))) float f32x4;

__device__ __forceinline__ short f2bf(float f) {
  union { float f; uint32_t u; } v; v.f = f;
  uint32_t u = v.u;
  u += 0x7FFF + ((u >> 16) & 1);   // round-to-nearest-even
  return (short)(u >> 16);
}

// ---- prologue: in_feats f32 -> bf16 ----
__global__ void cvt_feats(const float* __restrict__ in, short* __restrict__ out, int n8) {
  int i = blockIdx.x * blockDim.x + threadIdx.x;
  int stride = gridDim.x * blockDim.x;
  for (; i < n8; i += stride) {
    const float* p = in + (size_t)i * 8;
    f32x4 f0 = *(const f32x4*)(p);
    f32x4 f1 = *(const f32x4*)(p + 4);
    bf16x8 o;
    o[0] = f2bf(f0[0]); o[1] = f2bf(f0[1]); o[2] = f2bf(f0[2]); o[3] = f2bf(f0[3]);
    o[4] = f2bf(f1[0]); o[5] = f2bf(f1[1]); o[6] = f2bf(f1[2]); o[7] = f2bf(f1[3]);
    *(bf16x8*)(out + (size_t)i * 8) = o;
  }
}

// ---- prologue: W [27][64][64] f32 -> W^T bf16 as wt[k][j][i] ----
__global__ void cvt_w(const float* __restrict__ w, short* __restrict__ wt) {
  int k = blockIdx.x;
  const float* wk = w + (size_t)k * CDIM * CDIM;
  short* wtk = wt + (size_t)k * CDIM * CDIM;
  for (int t = threadIdx.x; t < CDIM * CDIM; t += blockDim.x) {
    int j = t >> 6, i = t & 63;
    wtk[j * CDIM + i] = f2bf(wk[i * CDIM + j]);
  }
}

// ---- bucket histogram: LDS-private per WG, flush plain stores ----
__global__ __launch_bounds__(256)
void k_hist(const int* __restrict__ om, unsigned int* __restrict__ hist_g) {
  __shared__ unsigned int h[NBKT];
  int wg = blockIdx.x, tid = threadIdx.x;
  for (int i = tid; i < NBKT; i += 256) h[i] = 0u;
  __syncthreads();
  int base = wg * CHUNK;
  int end = base + CHUNK; if (end > TOTALC) end = TOTALC;
  for (int i = base + tid; i < end; i += 256)
    atomicAdd(&h[((unsigned)om[i]) >> 7], 1u);
  __syncthreads();
  for (int i = tid; i < NBKT; i += 256)
    hist_g[(size_t)i * NWG1 + wg] = h[i];
}

// ---- 3-kernel exclusive scan over SCAN_N (bin-major [bkt][wg]) ----
__global__ void scan_local(const unsigned int* __restrict__ counts,
                           unsigned int* __restrict__ offsets,
                           unsigned int* __restrict__ bsum, int n) {
  __shared__ unsigned int sh[1024];
  int t = threadIdx.x;
  int idx = blockIdx.x * 1024 + t;
  unsigned int v = (idx < n) ? counts[idx] : 0u;
  sh[t] = v; __syncthreads();
  for (int o = 1; o < 1024; o <<= 1) {
    unsigned int u = (t >= o) ? sh[t - o] : 0u;
    __syncthreads();
    sh[t] += u;
    __syncthreads();
  }
  if (idx < n) offsets[idx] = sh[t] - v;
  if (t == 1023) bsum[blockIdx.x] = sh[1023];
}

__global__ void scan_bsum(unsigned int* __restrict__ bsum, int nb) {
  __shared__ unsigned int sh[1024];
  int t = threadIdx.x;
  unsigned int v = (t < nb) ? bsum[t] : 0u;
  sh[t] = v; __syncthreads();
  for (int o = 1; o < 1024; o <<= 1) {
    unsigned int u = (t >= o) ? sh[t - o] : 0u;
    __syncthreads();
    sh[t] += u;
    __syncthreads();
  }
  if (t < nb) bsum[t] = sh[t] - v;
}

__global__ void scan_apply(unsigned int* __restrict__ offsets,
                           const unsigned int* __restrict__ bsum, int n, unsigned int total) {
  int t = threadIdx.x;
  int idx = blockIdx.x * 1024 + t;
  if (idx < n) offsets[idx] += bsum[blockIdx.x];
  if (idx == 0) offsets[n] = total;
}

// ---- scatter packed entries to bucket-sorted order (LDS cursors only) ----
__global__ __launch_bounds__(256)
void k_scatter(const int* __restrict__ om, const int* __restrict__ im,
               const unsigned int* __restrict__ base_g, unsigned int* __restrict__ sorted_g) {
  __shared__ unsigned int cur[NBKT];
  int wg = blockIdx.x, tid = threadIdx.x;
  for (int i = tid; i < NBKT; i += 256) cur[i] = base_g[(size_t)i * NWG1 + wg];
  __syncthreads();
  int base = wg * CHUNK;
  int end = base + CHUNK; if (end > TOTALC) end = TOTALC;
  for (int i = base + tid; i < end; i += 256) {
    unsigned int o = (unsigned)om[i];
    unsigned int bkt = o >> 7;
    unsigned int outl = o & 127u;
    unsigned int kk = (unsigned)(i / MPAIRS);
    unsigned int inrow = (unsigned)im[i];
    unsigned int entry = (outl << 23) | (kk << 18) | inrow;
    unsigned int pos = atomicAdd(&cur[bkt], 1u);
    sorted_g[pos] = entry;
  }
}

// ---- fused bucket kernel: LDS counting-sort by k -> MFMA tiles -> LDS f32
// accumulate -> single coalesced output write. Zero global atomics. ----
__global__ __launch_bounds__(256, 3)
void k_bucket(const short* __restrict__ a_bf16,   // [NROWS][64] bf16
              const short* __restrict__ wt_bf16,  // [27][64 out][64 in] bf16
              const unsigned int* __restrict__ base_g,
              const unsigned int* __restrict__ sorted_g,
              float* __restrict__ out) {
  __shared__ float accum[(BROWS + 1) * 65];       // 129 rows x 65 (pad) = 33.5 KB
  __shared__ unsigned int ksorted[KCAP];          // 14.3 KB
  __shared__ unsigned int khist[KVOL];
  __shared__ unsigned int kbase_s[KVOL + 1];
  __shared__ unsigned int kcur[KVOL];

  const int bkt = blockIdx.x, tid = threadIdx.x;
  const int lane = tid & 63, wave = tid >> 6;
  const int r = lane & 15, h = lane >> 4;

  for (int i = tid; i < (BROWS + 1) * 65; i += 256) accum[i] = 0.f;
  if (tid < KVOL) khist[tid] = 0u;
  __syncthreads();

  const unsigned int s = base_g[(size_t)bkt * NWG1];
  const unsigned int e = base_g[(size_t)(bkt + 1) * NWG1];
  const int seglen = (int)(e - s);

  // pass 1: histogram by k
  for (int i = tid; i < seglen; i += 256)
    atomicAdd(&khist[(sorted_g[s + i] >> 18) & 31u], 1u);
  __syncthreads();
  if (tid == 0) {
    unsigned int run = 0;
    for (int kk = 0; kk < KVOL; ++kk) {
      kbase_s[kk] = run; kcur[kk] = run;
      run += (khist[kk] + 15u) & ~15u;           // pad each k-segment to x16
    }
    kbase_s[KVOL] = run;
  }
  __syncthreads();
  const int tot = (int)kbase_s[KVOL];
  for (int i = tid; i < tot; i += 256) ksorted[i] = DUMMY;
  __syncthreads();
  // pass 2: counting-sort scatter into LDS
  for (int i = tid; i < seglen; i += 256) {
    unsigned int ent = sorted_g[s + i];
    unsigned int pos = atomicAdd(&kcur[(ent >> 18) & 31u], 1u);
    ksorted[pos] = ent;
  }
  __syncthreads();

  // compute: per-k MFMA tiles, LDS f32 accumulation
  for (int kk = 0; kk < KVOL; ++kk) {
    const int kb = (int)kbase_s[kk];
    const int ntiles = ((int)kbase_s[kk + 1] - kb) >> 4;
    if (ntiles == 0) continue;
    const short* wtk = wt_bf16 + (size_t)kk * CDIM * CDIM;
    bf16x8 b[4][2];
#pragma unroll
    for (int t = 0; t < 4; ++t)
#pragma unroll
      for (int c = 0; c < 2; ++c)
        b[t][c] = *(const bf16x8*)(wtk + (t * 16 + r) * CDIM + c * 32 + h * 8);

    for (int tile = wave; tile < ntiles; tile += 4) {
      const unsigned int ent = ksorted[kb + tile * 16 + r];
      const unsigned int inrow = ent & 0x3FFFFu;
      const unsigned int outl = ent >> 23;       // 128 for dummies -> garbage row
      const short* arow = a_bf16 + (size_t)inrow * CDIM;
      bf16x8 a0 = *(const bf16x8*)(arow + h * 8);
      bf16x8 a1 = *(const bf16x8*)(arow + 32 + h * 8);

      f32x4 acc[4];
#pragma unroll
      for (int t = 0; t < 4; ++t) {
        acc[t] = (f32x4){0.f, 0.f, 0.f, 0.f};
        acc[t] = __builtin_amdgcn_mfma_f32_16x16x32_bf16(b[t][0], a0, acc[t], 0, 0, 0);
        acc[t] = __builtin_amdgcn_mfma_f32_16x16x32_bf16(b[t][1], a1, acc[t], 0, 0, 0);
      }
      // lane (r,h) holds channels t*16+h*4+{0..3} of this entry's contribution
      float* arr = &accum[outl * 65 + h * 4];
#pragma unroll
      for (int t = 0; t < 4; ++t) {
#pragma unroll
        for (int j = 0; j < 4; ++j)
          atomicAdd(&arr[t * 16 + j], acc[t][j]);
      }
    }
  }
  __syncthreads();

  // coalesced writeout (covers every output element; no memset needed)
  const int rowbase = bkt * BROWS;
  int valid = NROWS - rowbase; if (valid > BROWS) valid = BROWS;
  for (int sIdx = tid; sIdx < valid * 16; sIdx += 256) {
    int row = sIdx >> 4, c4 = sIdx & 15;
    const float* ap = &accum[row * 65 + c4 * 4];
    float4 v; v.x = ap[0]; v.y = ap[1]; v.z = ap[2]; v.w = ap[3];
    *(float4*)(out + ((size_t)(rowbase + row)) * CDIM + c4 * 4) = v;
  }
}

extern "C" void kernel_launch(void* const* d_in, const int* in_sizes, int n_in,
                              void* d_out, int out_size, void* d_ws, size_t ws_size,
                              hipStream_t stream) {
  const float* in_feats = (const float*)d_in[0];   // [200000][64]
  const float* kernel   = (const float*)d_in[1];   // [27][64][64]
  const int*   in_map   = (const int*)d_in[2];     // [27][150000]
  const int*   out_map  = (const int*)d_in[3];     // [27][150000]
  float* out = (float*)d_out;                      // [200000][64]

  uint8_t* ws = (uint8_t*)d_ws;
  size_t off = 0;
  auto alloc = [&](size_t bytes) -> void* {
    void* p = ws + off;
    off += (bytes + 255) & ~(size_t)255;
    return p;
  };
  short* in_bf16         = (short*)alloc((size_t)NROWS * CDIM * 2);        // 25.6 MB
  short* wt_bf16         = (short*)alloc((size_t)KVOL * CDIM * CDIM * 2);  // 221 KB
  unsigned int* hist_g   = (unsigned int*)alloc((size_t)SCAN_N * 4);       // 1.6 MB
  unsigned int* base_g   = (unsigned int*)alloc((size_t)(SCAN_N + 1) * 4); // 1.6 MB
  unsigned int* bsum     = (unsigned int*)alloc(4096);
  unsigned int* sorted_g = (unsigned int*)alloc((size_t)TOTALC * 4);       // 16.2 MB

  cvt_feats<<<2048, 256, 0, stream>>>(in_feats, in_bf16, NROWS * CDIM / 8);
  cvt_w<<<KVOL, 256, 0, stream>>>(kernel, wt_bf16);

  k_hist<<<NWG1, 256, 0, stream>>>(out_map, hist_g);

  const int sb = (SCAN_N + 1023) / 1024;   // 391
  scan_local<<<sb, 1024, 0, stream>>>(hist_g, base_g, bsum, SCAN_N);
  scan_bsum<<<1, 1024, 0, stream>>>(bsum, sb);
  scan_apply<<<sb, 1024, 0, stream>>>(base_g, bsum, SCAN_N, (unsigned int)TOTALC);

  k_scatter<<<NWG1, 256, 0, stream>>>(out_map, in_map, base_g, sorted_g);

  k_bucket<<<NBKT, 256, 0, stream>>>(in_bf16, wt_bf16, base_g, sorted_g, out);
}

// Round 7
// 1697.641 us; speedup vs baseline: 1.0338x; 1.0338x over previous
//
#include <hip/hip_runtime.h>
#include <hip/hip_bf16.h>
#include <hip/hip_fp16.h>
#include <stdint.h>

// Problem constants (from reference)
#define KVOL   27
#define MPAIRS 150000
#define NROWS  200000            // N_IN == N_OUT
#define CDIM   64

typedef __attribute__((ext_vector_type(8))) short bf16x8;   // 8 bf16 = 4 VGPRs
typedef __attribute__((ext_vector_type(4))) float f32x4;

__device__ __forceinline__ short f2bf(float f) {
  union { float f; uint32_t u; } v; v.f = f;
  uint32_t u = v.u;
  u += 0x7FFF + ((u >> 16) & 1);   // round-to-nearest-even
  return (short)(u >> 16);
}

// ---- prologue: in_feats f32 -> bf16 ----
__global__ void cvt_feats(const float* __restrict__ in, short* __restrict__ out, int n8) {
  int i = blockIdx.x * blockDim.x + threadIdx.x;
  int stride = gridDim.x * blockDim.x;
  for (; i < n8; i += stride) {
    const float* p = in + (size_t)i * 8;
    f32x4 f0 = *(const f32x4*)(p);
    f32x4 f1 = *(const f32x4*)(p + 4);
    bf16x8 o;
    o[0] = f2bf(f0[0]); o[1] = f2bf(f0[1]); o[2] = f2bf(f0[2]); o[3] = f2bf(f0[3]);
    o[4] = f2bf(f1[0]); o[5] = f2bf(f1[1]); o[6] = f2bf(f1[2]); o[7] = f2bf(f1[3]);
    *(bf16x8*)(out + (size_t)i * 8) = o;
  }
}

// ---- prologue: W [27][64][64] f32 -> W^T bf16 as wt[k][j][i] ----
__global__ void cvt_w(const float* __restrict__ w, short* __restrict__ wt) {
  int k = blockIdx.x;
  const float* wk = w + (size_t)k * CDIM * CDIM;
  short* wtk = wt + (size_t)k * CDIM * CDIM;
  for (int t = threadIdx.x; t < CDIM * CDIM; t += blockDim.x) {
    int j = t >> 6, i = t & 63;
    wtk[j * CDIM + i] = f2bf(wk[i * CDIM + j]);
  }
}

// ---- main: per offset k, tiles of 16 pairs.
// Swapped MFMA (D' = W^T x X^T): lane (r,h) owns pair base+r,
// channels t*16+h*4+{0..3} -> 4 contiguous channels per t-tile.
// Scatter-add via PACKED f16 atomics (2 channels/op -> 32 ops/pair vs 64).
__global__ __launch_bounds__(256, 4)
void spconv_mfma(const short* __restrict__ a_bf16,   // [NROWS][64] bf16
                 const short* __restrict__ wt_bf16,  // [27][64 out][64 in] bf16
                 const int*   __restrict__ in_map,   // [27][M]
                 const int*   __restrict__ out_map,  // [27][M]
                 __half*      __restrict__ accf16)   // [NROWS][64] f16 accumulator
{
  const int k    = blockIdx.y;
  const int lane = threadIdx.x & 63;
  const int wave = threadIdx.x >> 6;        // 0..3
  const int r    = lane & 15;               // pair selector / fragment row
  const int h    = lane >> 4;               // 0..3

  // W^T fragments (A operand): A[m][kk]: m = t*16 + r (out ch), kk = c*32 + h*8 + e
  bf16x8 b[4][2];
  const short* wtk = wt_bf16 + (size_t)k * CDIM * CDIM;
#pragma unroll
  for (int t = 0; t < 4; ++t)
#pragma unroll
    for (int c = 0; c < 2; ++c)
      b[t][c] = *(const bf16x8*)(wtk + (t * 16 + r) * CDIM + c * 32 + h * 8);

  const int* imk = in_map  + (size_t)k * MPAIRS;
  const int* omk = out_map + (size_t)k * MPAIRS;
  const int ntiles = MPAIRS / 16;           // 9375, exact
  const int wstride = gridDim.x * 4;

  for (int tile = blockIdx.x * 4 + wave; tile < ntiles; tile += wstride) {
    const int base = tile * 16;
    // B operand (X^T): B[kk][n]: n = r (pair), kk = c*32 + h*8 + e
    const int in_row = imk[base + r];
    const int orow   = omk[base + r];
    const short* arow = a_bf16 + (size_t)in_row * CDIM;
    bf16x8 a0 = *(const bf16x8*)(arow + h * 8);
    bf16x8 a1 = *(const bf16x8*)(arow + 32 + h * 8);

    f32x4 acc[4];
#pragma unroll
    for (int t = 0; t < 4; ++t) {
      acc[t] = (f32x4){0.f, 0.f, 0.f, 0.f};
      acc[t] = __builtin_amdgcn_mfma_f32_16x16x32_bf16(b[t][0], a0, acc[t], 0, 0, 0);
      acc[t] = __builtin_amdgcn_mfma_f32_16x16x32_bf16(b[t][1], a1, acc[t], 0, 0, 0);
    }

    // Lane owns row `orow`, channels t*16 + h*4 + {0..3}. Packed f16 scatter-add.
    __half* arp = accf16 + (size_t)orow * CDIM + h * 4;
#pragma unroll
    for (int t = 0; t < 4; ++t) {
      __half2 lo = __floats2half2_rn(acc[t][0], acc[t][1]);
      __half2 hi = __floats2half2_rn(acc[t][2], acc[t][3]);
      unsafeAtomicAdd((__half2*)(arp + t * 16), lo);
      unsafeAtomicAdd((__half2*)(arp + t * 16 + 2), hi);
    }
  }
}

// ---- epilogue: f16 accumulator -> f32 output (fully overwrites d_out) ----
__global__ void cvt_out(const __half* __restrict__ acc, float* __restrict__ out, int n8) {
  int i = blockIdx.x * blockDim.x + threadIdx.x;
  int stride = gridDim.x * blockDim.x;
  for (; i < n8; i += stride) {
    const __half2* p = (const __half2*)(acc + (size_t)i * 8);
    float* q = out + (size_t)i * 8;
    float4 o0, o1;
    float2 v0 = __half22float2(p[0]);
    float2 v1 = __half22float2(p[1]);
    float2 v2 = __half22float2(p[2]);
    float2 v3 = __half22float2(p[3]);
    o0.x = v0.x; o0.y = v0.y; o0.z = v1.x; o0.w = v1.y;
    o1.x = v2.x; o1.y = v2.y; o1.z = v3.x; o1.w = v3.y;
    *(float4*)(q) = o0;
    *(float4*)(q + 4) = o1;
  }
}

extern "C" void kernel_launch(void* const* d_in, const int* in_sizes, int n_in,
                              void* d_out, int out_size, void* d_ws, size_t ws_size,
                              hipStream_t stream) {
  const float* in_feats = (const float*)d_in[0];   // [200000][64]
  const float* kernel   = (const float*)d_in[1];   // [27][64][64]
  const int*   in_map   = (const int*)d_in[2];     // [27][150000]
  const int*   out_map  = (const int*)d_in[3];     // [27][150000]
  float* out = (float*)d_out;                      // [200000][64]

  uint8_t* ws = (uint8_t*)d_ws;
  size_t off = 0;
  auto alloc = [&](size_t bytes) -> void* {
    void* p = ws + off;
    off += (bytes + 255) & ~(size_t)255;
    return p;
  };
  short*  in_bf16 = (short*)alloc((size_t)NROWS * CDIM * 2);        // 25.6 MB
  short*  wt_bf16 = (short*)alloc((size_t)KVOL * CDIM * CDIM * 2);  // 221 KB
  __half* accf16  = (__half*)alloc((size_t)NROWS * CDIM * 2);       // 25.6 MB

  // zero the f16 accumulator (d_out itself is fully overwritten by cvt_out)
  hipMemsetAsync(accf16, 0, (size_t)NROWS * CDIM * 2, stream);

  cvt_feats<<<2048, 256, 0, stream>>>(in_feats, in_bf16, NROWS * CDIM / 8);
  cvt_w<<<KVOL, 256, 0, stream>>>(kernel, wt_bf16);

  dim3 grid(96, KVOL);
  spconv_mfma<<<grid, 256, 0, stream>>>(in_bf16, wt_bf16, in_map, out_map, accf16);

  cvt_out<<<2048, 256, 0, stream>>>(accf16, out, NROWS * CDIM / 8);
}